// Round 2
// baseline (80.730 us; speedup 1.0000x reference)
//
#include <hip/hip_runtime.h>
#include <type_traits>
#include <utility>

#define CDIM   45
#define LMAXX  8
#define WAVES_PB 4
#define VOXPB  64
#define VDIM   64
#define VPT    (VDIM / WAVES_PB)

// ---------------- compile-time SH constant tables ----------------
constexpr double PI_D = 3.14159265358979323846;

constexpr double dfactd(int n){ double o=1.0; for(int k=n;k>1;k-=2) o*=k; return o; }
constexpr double factd (int n){ double o=1.0; for(int k=2;k<=n;++k) o*=k; return o; }
constexpr double csqrtd(double x){
  if(x<=0.0) return 0.0;
  double g = x>1.0 ? x : 1.0;
  for(int i=0;i<200;++i) g = 0.5*(g + x/g);
  return g;
}

struct SHTab {
  float c1[LMAXX+1][LMAXX+1];  // (2l-1)/(l-m)
  float c2[LMAXX+1][LMAXX+1];  // (l+m-1)/(l-m)
  float qmm[LMAXX+1];          // (-1)^m (2m-1)!!
  float qnx[LMAXX+1];          // (2m+1)*qmm
  float CP [LMAXX+1][LMAXX+1]; // combined: m==0 ? K : sgn*sqrt2*K
};

constexpr SHTab makeTab(){
  SHTab t{};
  for(int m=0;m<=LMAXX;++m){
    double q = ((m&1)?-1.0:1.0)*dfactd(2*m-1);
    t.qmm[m]=(float)q;
    t.qnx[m]=(float)((2.0*m+1.0)*q);
    for(int l=m+2;l<=LMAXX;++l){
      t.c1[m][l]=(float)((2.0*l-1.0)/(double)(l-m));
      t.c2[m][l]=(float)((double)(l+m-1)/(double)(l-m));
    }
    for(int l=m;l<=LMAXX;++l){
      double K = csqrtd((2.0*l+1.0)/(4.0*PI_D)*factd(l-m)/factd(l+m));
      double v = (m==0)? K : (((m&1)?-1.0:1.0)*csqrtd(2.0)*K);
      t.CP[m][l]=(float)v;
    }
  }
  return t;
}
constexpr SHTab SHT = makeTab();

// block offsets for even l: l=0,2,4,6,8 -> 0,1,6,15,28 ; idx(l,m)=offL(l)+l+m
constexpr int offL(int l){ return l==0?0 : (l==2?1 : (l==4?6 : (l==6?15 : 28))); }

// compile-time unroller (indices are constants -> acc[] stays in registers)
template<int N, typename F>
__device__ __forceinline__ void cunroll(F&& f){
  if constexpr (N > 0){
    cunroll<N-1>(f);
    f(std::integral_constant<int, N-1>{});
  }
}

// ---------------- kernel ----------------
__global__ __launch_bounds__(256, 2)
void fodf_reorient_kernel(const float* __restrict__ image,
                          const float* __restrict__ affine,
                          const float* __restrict__ psf,
                          const float* __restrict__ Mp,
                          float* __restrict__ out,
                          int Nvox)
{
  __shared__ float red[WAVES_PB][VOXPB][CDIM+3];   // pad 45->48 floats

  const int tid  = threadIdx.x;
  const int lane = tid & 63;
  const int wvi  = __builtin_amdgcn_readfirstlane(tid >> 6); // wave id 0..3 (uniform)
  const int voxBase = blockIdx.x * VOXPB;
  const int vox  = voxBase + lane;
  const bool valid = vox < Nvox;

  // ---- per-voxel loads (one lane = one voxel) ----
  float img[CDIM];
  if (valid){
    const float* ip = image + (long long)vox * CDIM;
    #pragma unroll
    for(int c=0;c<CDIM;++c) img[c] = ip[c];
  } else {
    #pragma unroll
    for(int c=0;c<CDIM;++c) img[c] = 0.0f;
  }

  float a[9];
  if (valid){
    const float* ap = affine + (long long)vox * 9;
    #pragma unroll
    for(int i=0;i<9;++i) a[i] = ap[i];
  } else {
    #pragma unroll
    for(int i=0;i<9;++i) a[i] = (i%4==0) ? 1.0f : 0.0f;   // identity
  }

  // ---- 3x3 inverse via adjugate ----
  const float det = a[0]*(a[4]*a[8]-a[5]*a[7])
                  - a[1]*(a[3]*a[8]-a[5]*a[6])
                  + a[2]*(a[3]*a[7]-a[4]*a[6]);
  const float rdet = 1.0f/det;
  const float i00 =  (a[4]*a[8]-a[5]*a[7])*rdet;
  const float i01 = -(a[1]*a[8]-a[2]*a[7])*rdet;
  const float i02 =  (a[1]*a[5]-a[2]*a[4])*rdet;
  const float i10 = -(a[3]*a[8]-a[5]*a[6])*rdet;
  const float i11 =  (a[0]*a[8]-a[2]*a[6])*rdet;
  const float i12 = -(a[0]*a[5]-a[2]*a[3])*rdet;
  const float i20 =  (a[3]*a[7]-a[4]*a[6])*rdet;
  const float i21 = -(a[0]*a[7]-a[1]*a[6])*rdet;
  const float i22 =  (a[0]*a[4]-a[1]*a[3])*rdet;

  float acc[CDIM];
  #pragma unroll
  for(int c=0;c<CDIM;++c) acc[c]=0.0f;

  // ---- loop over this wave's 16 PSF vectors (v is wave-uniform -> s_loads) ----
  const int vbase = wvi * VPT;
  #pragma unroll 2
  for(int k=0;k<VPT;++k){
    const int v = vbase + k;
    const float sxv = psf[3*v+0];
    const float syv = psf[3*v+1];
    const float szv = psf[3*v+2];

    // vi_hat = A^{-1} @ psf[v]
    const float hx = fmaf(i00,sxv, fmaf(i01,syv, i02*szv));
    const float hy = fmaf(i10,sxv, fmaf(i11,syv, i12*szv));
    const float hz = fmaf(i20,sxv, fmaf(i21,syv, i22*szv));

    const float r2  = fmaf(hx,hx, fmaf(hy,hy, hz*hz));
    const float r2e = r2 + 1e-12f;
    float rin = rsqrtf(r2e);
    rin = rin * (1.5f - 0.5f*r2e*rin*rin);        // Newton refine
    // xyz -> yzx permute, then normalize
    const float px = hy*rin;
    const float py = hz*rin;
    const float pz = hx*rin;

    const float modv = sqrtf(r2) * det;           // |vi_hat| / det(A^{-1})

    // w[v] = dot(M_p[v,:], img) — M_p row is wave-uniform (SGPR broadcast)
    const float* Mrow = Mp + v*CDIM;
    float w0=0.f,w1=0.f,w2=0.f,w3=0.f;
    #pragma unroll
    for(int c=0;c<44;c+=4){
      w0 = fmaf(Mrow[c+0], img[c+0], w0);
      w1 = fmaf(Mrow[c+1], img[c+1], w1);
      w2 = fmaf(Mrow[c+2], img[c+2], w2);
      w3 = fmaf(Mrow[c+3], img[c+3], w3);
    }
    w0 = fmaf(Mrow[44], img[44], w0);
    const float wval = (w0+w1)+(w2+w3);
    const float wmod = modv * wval;

    // A_m, B_m recurrence (Chebyshev)
    float Aa[LMAXX+1], Bb[LMAXX+1];
    Aa[0]=1.0f; Bb[0]=0.0f;
    cunroll<LMAXX>([&](auto Mc){
      constexpr int M = decltype(Mc)::value + 1;
      Aa[M] = fmaf(px, Aa[M-1], -(py*Bb[M-1]));
      Bb[M] = fmaf(px, Bb[M-1],  (py*Aa[M-1]));
    });

    // per |m|: Q recurrence + fused accumulate into acc[]
    cunroll<LMAXX+1>([&](auto AMc){
      constexpr int AM = decltype(AMc)::value;
      const float fa = wmod * Aa[AM];
      const float fb = wmod * Bb[AM];
      float qp2 = SHT.qmm[AM];        // Q[AM][AM]
      float qp1 = SHT.qnx[AM]*pz;     // Q[AM+1][AM]

      if constexpr ((AM&1)==0){       // l = AM (even): emit
        constexpr float C = SHT.CP[AM][AM];
        const float t = qp2 * C;
        if constexpr (AM==0){
          acc[0] = fmaf(t, wmod, acc[0]);
        } else {
          acc[offL(AM)+2*AM] = fmaf(t, fa, acc[offL(AM)+2*AM]);
          acc[offL(AM)+0   ] = fmaf(t, fb, acc[offL(AM)+0   ]);
        }
      }
      if constexpr (AM<LMAXX && (((AM+1)&1)==0)){  // l = AM+1 even
        constexpr int L = AM+1;
        constexpr float C = SHT.CP[AM][L];
        const float t = qp1 * C;
        acc[offL(L)+L+AM] = fmaf(t, fa, acc[offL(L)+L+AM]);
        acc[offL(L)+L-AM] = fmaf(t, fb, acc[offL(L)+L-AM]);
      }

      constexpr int CNT = (LMAXX-AM-1) > 0 ? (LMAXX-AM-1) : 0;  // l = AM+2..8
      cunroll<CNT>([&](auto Lc){
        constexpr int L = AM + 2 + decltype(Lc)::value;
        constexpr float C1 = SHT.c1[AM][L];
        constexpr float C2 = SHT.c2[AM][L];
        const float q = fmaf(C1*pz, qp1, -(C2*qp2));
        qp2 = qp1; qp1 = q;
        if constexpr ((L&1)==0){
          constexpr float C = SHT.CP[AM][L];
          const float t = q * C;
          if constexpr (AM==0){
            acc[offL(L)+L] = fmaf(t, wmod, acc[offL(L)+L]);
          } else {
            acc[offL(L)+L+AM] = fmaf(t, fa, acc[offL(L)+L+AM]);
            acc[offL(L)+L-AM] = fmaf(t, fb, acc[offL(L)+L-AM]);
          }
        }
      });
    });
  }

  // ---- cross-wave reduction over the 4 vector-splits ----
  #pragma unroll
  for(int c=0;c<CDIM;++c) red[wvi][lane][c] = acc[c];
  __syncthreads();

  const int total = VOXPB * CDIM;
  for(int i = tid; i < total; i += 256){
    const int vx = i / CDIM;
    if (voxBase + vx < Nvox){
      const int c = i - vx*CDIM;
      const float s = red[0][vx][c] + red[1][vx][c]
                    + red[2][vx][c] + red[3][vx][c];
      out[(long long)voxBase*CDIM + i] = s;
    }
  }
}

// ---------------- launch ----------------
extern "C" void kernel_launch(void* const* d_in, const int* in_sizes, int n_in,
                              void* d_out, int out_size, void* d_ws, size_t ws_size,
                              hipStream_t stream)
{
  const float* image  = (const float*)d_in[0];
  const float* affine = (const float*)d_in[1];
  const float* psf    = (const float*)d_in[2];
  const float* Mp     = (const float*)d_in[3];
  float* out = (float*)d_out;

  const int Nvox = in_sizes[0] / CDIM;
  const int blocks = (Nvox + VOXPB - 1) / VOXPB;

  hipLaunchKernelGGL(fodf_reorient_kernel, dim3(blocks), dim3(256), 0, stream,
                     image, affine, psf, Mp, out, Nvox);
}